// Round 7
// baseline (359.537 us; speedup 1.0000x reference)
//
#include <hip/hip_runtime.h>
#include <hip/hip_cooperative_groups.h>

namespace cg = cooperative_groups;

#define L_SEQ 2048
#define D_DIM 768
#define N_ST 16
#define NB 4
#define NJ 33   // 16 B + 16 C + 1 s1
#define NROWS (NB * L_SEQ)          // 8192
#define PROJ_ELEMS (NROWS * NJ)     // 270336
#define DN (D_DIM * N_ST)           // 12288

// proj GEMM tiling
#define DSPLIT 8
#define DSEG (D_DIM / DSPLIT)       // 96
#define DK 32
#define NCHUNK (DSEG / DK)          // 3
#define RB 128                      // rows per block
#define XST 132
#define WST 64

typedef float v2f __attribute__((ext_vector_type(2)));

__device__ __forceinline__ float fast_exp2(float x) {
#if __has_builtin(__builtin_amdgcn_exp2f)
  return __builtin_amdgcn_exp2f(x);
#else
  return __expf(x * 0.69314718055994531f);
#endif
}

// softplus = log2(1+2^(v*log2e))*ln2; guard large v (exp2 -> inf)
__device__ __forceinline__ float softplus_f(float v) {
  float e = fast_exp2(v * 1.44269504088896f);
  float l = __log2f(1.0f + e) * 0.69314718055994531f;
  return (v > 15.0f) ? v : l;
}

// pw2[k] = {e1^(2k+1), e1^(2k+2)} via log-depth tree
__device__ __forceinline__ void pow_tree2(float e1, v2f pw2[8]) {
  float e2s = e1 * e1;
  float e4s = e2s * e2s;
  float e8s = e4s * e4s;
  v2f s2 = {e2s, e2s}, s4 = {e4s, e4s}, s8 = {e8s, e8s};
  pw2[0] = (v2f){e1, e2s};
  pw2[1] = pw2[0] * s2;
  pw2[2] = pw2[0] * s4;
  pw2[3] = pw2[1] * s4;
  pw2[4] = pw2[0] * s8;
  pw2[5] = pw2[1] * s8;
  pw2[6] = pw2[2] * s8;
  pw2[7] = pw2[3] * s8;
}

// scalar tree (non-geom fallback kernels)
__device__ __forceinline__ void pow_tree(float e1, float pw[N_ST]) {
  pw[0] = e1;  pw[1] = pw[0]*pw[0];  pw[2] = pw[1]*pw[0];  pw[3] = pw[1]*pw[1];
  pw[4] = pw[3]*pw[0]; pw[5] = pw[3]*pw[1]; pw[6] = pw[3]*pw[2]; pw[7] = pw[3]*pw[3];
  pw[8] = pw[7]*pw[0]; pw[9] = pw[7]*pw[1]; pw[10]= pw[7]*pw[2]; pw[11]= pw[7]*pw[3];
  pw[12]= pw[7]*pw[4]; pw[13]= pw[7]*pw[5]; pw[14]= pw[7]*pw[6]; pw[15]= pw[7]*pw[7];
}

// ---------------------------------------------------------------------------
// Projection GEMM, K-split 8 ways. (Verified round 3.)
// ---------------------------------------------------------------------------
__global__ __launch_bounds__(256) void k_proj_gemm(
    const float* __restrict__ x, const float* __restrict__ W_bc,
    const float* __restrict__ W_1, float* __restrict__ PBC) {
  __shared__ float xs_t[DK * XST];
  __shared__ float ws_t[DK * WST];

  const int ds  = blockIdx.x % DSPLIT;
  const int rb0 = (blockIdx.x / DSPLIT) * RB;
  const int dbase = ds * DSEG;
  const int tid = threadIdx.x;
  const int rg = tid & 31;
  const int jg = tid >> 5;

  float acc[4][5];
#pragma unroll
  for (int i = 0; i < 4; ++i)
#pragma unroll
    for (int k = 0; k < 5; ++k) acc[i][k] = 0.0f;

  const int lrow = tid >> 1;
  const int lhalf = (tid & 1) * 16;
  const float* xg_row = x + (size_t)(rb0 + lrow) * D_DIM + dbase + lhalf;

  for (int ch = 0; ch < NCHUNK; ++ch) {
    const int dc = dbase + ch * DK;
    float4 xv[4];
#pragma unroll
    for (int q = 0; q < 4; ++q)
      xv[q] = *(const float4*)(xg_row + ch * DK + q * 4);
    float wv[8];
    int widx[8];
#pragma unroll
    for (int u = 0; u < 8; ++u) {
      int idx = tid + u * 256;
      int dk = idx >> 6, slot = idx & 63;
      int wjg = slot >> 3, wk = slot & 7;
      int j = wjg + 8 * wk;
      float v = 0.0f;
      if (wk < 5) {
        if (j < 32)       v = W_bc[(size_t)j * D_DIM + dc + dk];
        else if (j == 32) v = W_1[dc + dk];
      }
      wv[u] = v; widx[u] = dk * WST + slot;
    }
    __syncthreads();
#pragma unroll
    for (int q = 0; q < 4; ++q) {
      xs_t[(lhalf + q * 4 + 0) * XST + lrow] = xv[q].x;
      xs_t[(lhalf + q * 4 + 1) * XST + lrow] = xv[q].y;
      xs_t[(lhalf + q * 4 + 2) * XST + lrow] = xv[q].z;
      xs_t[(lhalf + q * 4 + 3) * XST + lrow] = xv[q].w;
    }
#pragma unroll
    for (int u = 0; u < 8; ++u) ws_t[widx[u]] = wv[u];
    __syncthreads();
#pragma unroll 8
    for (int dk = 0; dk < DK; ++dk) {
      float4 xr = *(const float4*)&xs_t[dk * XST + rg * 4];
      float4 wr = *(const float4*)&ws_t[dk * WST + jg * 8];
      float w4  = ws_t[dk * WST + jg * 8 + 4];
      float xa[4] = {xr.x, xr.y, xr.z, xr.w};
      float wa[5] = {wr.x, wr.y, wr.z, wr.w, w4};
#pragma unroll
      for (int i = 0; i < 4; ++i)
#pragma unroll
        for (int k = 0; k < 5; ++k)
          acc[i][k] = fmaf(xa[i], wa[k], acc[i][k]);
    }
  }

  float* pb = PBC + (size_t)ds * PROJ_ELEMS;
#pragma unroll
  for (int i = 0; i < 4; ++i) {
    int row = rb0 + rg * 4 + i;
#pragma unroll
    for (int k = 0; k < 5; ++k) {
      int j = jg + 8 * k;
      if (k < 4 || jg == 0) pb[(size_t)row * NJ + j] = acc[i][k];
    }
  }
}

__global__ __launch_bounds__(256) void k_proj_reduce(
    const float* __restrict__ PBC, const float* __restrict__ b_bc,
    const float* __restrict__ b_1, float* __restrict__ BC33) {
  const int idx = blockIdx.x * 256 + threadIdx.x;
  const int j = idx % NJ;
  float s = 0.0f;
#pragma unroll
  for (int k = 0; k < DSPLIT; ++k) s += PBC[(size_t)k * PROJ_ELEMS + idx];
  s += (j < 32) ? b_bc[j] : b_1[0];
  BC33[idx] = s;
}

// ---------------------------------------------------------------------------
// Fused cooperative scan: phase A local scan (y -> LDS, H/DS -> global),
// grid.sync, phase B combine (192 blocks, 8-deep prefetch), grid.sync,
// phase C correction-only from LDS y.
// ---------------------------------------------------------------------------
template <int LC>
__global__ __launch_bounds__(256) void k_scan_coop(
    const float* __restrict__ x, const float* __restrict__ A_log,
    const float* __restrict__ W_d, const float* __restrict__ b_d,
    const float* __restrict__ BC33, float* __restrict__ DS,
    float* __restrict__ H, float* __restrict__ out) {
  constexpr int NC = L_SEQ / LC;
  __shared__ float ylds[LC * 256];
  const int tid = threadIdx.x;
  const int bid = blockIdx.x;
  const int cb = bid % 3;
  const int c  = (bid / 3) % NC;
  const int b  = bid / (3 * NC);
  const int d  = cb * 256 + tid;

  const float wd = W_d[d], bd = b_d[d];
  float Aln[N_ST];
  {
    const float4* al4 = (const float4*)(A_log + (size_t)d * N_ST);
#pragma unroll
    for (int q = 0; q < 4; ++q) {
      float4 v = al4[q];
      Aln[4*q+0] = -__expf(v.x) * 1.44269504088896f;
      Aln[4*q+1] = -__expf(v.y) * 1.44269504088896f;
      Aln[4*q+2] = -__expf(v.z) * 1.44269504088896f;
      Aln[4*q+3] = -__expf(v.w) * 1.44269504088896f;
    }
  }
  bool geom = true;
#pragma unroll
  for (int n = 1; n < N_ST; ++n) {
    float ref = (float)(n + 1) * Aln[0];
    geom = geom && (fabsf(Aln[n] - ref) <= 1e-4f * fabsf(ref) + 1e-12f);
  }
  const float a0 = Aln[0];

  const int l0 = c * LC;
  const float* bc = BC33 + (size_t)(b * L_SEQ + l0) * NJ;
  const float* xp = x + (size_t)(b * L_SEQ + l0) * D_DIM + d;

  // ---------------- phase A: local scan ----------------
  v2f h2[8];
#pragma unroll
  for (int k = 0; k < 8; ++k) h2[k] = (v2f){0.0f, 0.0f};
  float dsum = 0.0f;

  if (geom) {
#pragma unroll 8
    for (int l = 0; l < LC; ++l) {
      float s1 = bc[l * NJ + 32];
      float delta = softplus_f(fmaf(s1, wd, bd));
      float xv = xp[(size_t)l * D_DIM];
      float f = delta * xv;
      dsum += delta;
      v2f pw2[8];
      pow_tree2(fast_exp2(a0 * delta), pw2);
      v2f f2 = {f, f};
      v2f y2 = {0.0f, 0.0f};
#pragma unroll
      for (int k = 0; k < 8; ++k) {
        v2f B2 = {bc[l * NJ + 2*k], bc[l * NJ + 2*k + 1]};
        v2f C2 = {bc[l * NJ + 16 + 2*k], bc[l * NJ + 16 + 2*k + 1]};
        h2[k] = pw2[k] * h2[k] + f2 * B2;
        y2 = y2 + h2[k] * C2;
      }
      ylds[l * 256 + tid] = y2.x + y2.y;
    }
  } else {
#pragma unroll 4
    for (int l = 0; l < LC; ++l) {
      float s1 = bc[l * NJ + 32];
      float delta = softplus_f(fmaf(s1, wd, bd));
      float xv = xp[(size_t)l * D_DIM];
      float f = delta * xv;
      dsum += delta;
      float y = 0.0f;
#pragma unroll
      for (int k = 0; k < 8; ++k) {
        float dA0 = fast_exp2(delta * Aln[2*k]);
        float dA1 = fast_exp2(delta * Aln[2*k+1]);
        h2[k].x = fmaf(dA0, h2[k].x, f * bc[l * NJ + 2*k]);
        h2[k].y = fmaf(dA1, h2[k].y, f * bc[l * NJ + 2*k + 1]);
        y = fmaf(h2[k].x, bc[l * NJ + 16 + 2*k], y);
        y = fmaf(h2[k].y, bc[l * NJ + 16 + 2*k + 1], y);
      }
      ylds[l * 256 + tid] = y;
    }
  }

  DS[((size_t)b * NC + c) * D_DIM + d] = dsum;
  {
    size_t base = ((size_t)(b * NC + c) * D_DIM + d) * N_ST;
    float4* H4 = (float4*)(H + base);
#pragma unroll
    for (int q = 0; q < 4; ++q)
      H4[q] = make_float4(h2[2*q].x, h2[2*q].y, h2[2*q+1].x, h2[2*q+1].y);
  }

  cg::this_grid().sync();

  // ---------------- phase B: combine (192 blocks) ----------------
  if (bid < 192) {
    const int bb = bid / 48;
    const int tl = (bid % 48) * 256 + tid;          // 0..12287
    const int dd = tl >> 4, nn = tl & 15;
    const float Aln1 = -__expf(A_log[dd * N_ST + nn]) * 1.44269504088896f;
    const float* dsp = DS + (size_t)bb * NC * D_DIM + dd;
    float* Hp = H + (size_t)bb * NC * DN + tl;

    float h = 0.0f;
    float pds[8], ph[8];
#pragma unroll
    for (int k = 0; k < 8; ++k) {
      pds[k] = dsp[(size_t)k * D_DIM];
      ph[k]  = Hp[(size_t)k * DN];
    }
    for (int g = 0; g < NC; g += 8) {
      float nds[8], nh[8];
      if (g + 8 < NC) {
#pragma unroll
        for (int k = 0; k < 8; ++k) {
          nds[k] = dsp[(size_t)(g + 8 + k) * D_DIM];
          nh[k]  = Hp[(size_t)(g + 8 + k) * DN];
        }
      }
#pragma unroll
      for (int k = 0; k < 8; ++k) {
        float p = fast_exp2(Aln1 * pds[k]);
        Hp[(size_t)(g + k) * DN] = h;                // incoming state
        h = fmaf(p, h, ph[k]);
      }
#pragma unroll
      for (int k = 0; k < 8; ++k) { pds[k] = nds[k]; ph[k] = nh[k]; }
    }
  }

  cg::this_grid().sync();

  // ---------------- phase C: correction + output ----------------
  float* op = out + (size_t)(b * L_SEQ + l0) * D_DIM + d;
  if (c == 0) {
#pragma unroll 8
    for (int l = 0; l < LC; ++l)
      op[(size_t)l * D_DIM] = ylds[l * 256 + tid];
    return;
  }

  v2f hin2[8];
  {
    size_t base = ((size_t)(b * NC + c) * D_DIM + d) * N_ST;
    const float4* HIN4 = (const float4*)(H + base);
#pragma unroll
    for (int q = 0; q < 4; ++q) {
      float4 v = HIN4[q];
      hin2[2*q]   = (v2f){v.x, v.y};
      hin2[2*q+1] = (v2f){v.z, v.w};
    }
  }

  if (geom) {
    float S = 0.0f;
#pragma unroll 8
    for (int l = 0; l < LC; ++l) {
      float s1 = bc[l * NJ + 32];
      float delta = softplus_f(fmaf(s1, wd, bd));
      S += delta;
      v2f pw2[8];
      pow_tree2(fast_exp2(a0 * S), pw2);
      v2f acc = {0.0f, 0.0f};
#pragma unroll
      for (int k = 0; k < 8; ++k) {
        v2f C2 = {bc[l * NJ + 16 + 2*k], bc[l * NJ + 16 + 2*k + 1]};
        acc = acc + pw2[k] * (hin2[k] * C2);
      }
      op[(size_t)l * D_DIM] = ylds[l * 256 + tid] + acc.x + acc.y;
    }
  } else {
    float S = 0.0f;
#pragma unroll 4
    for (int l = 0; l < LC; ++l) {
      float s1 = bc[l * NJ + 32];
      float delta = softplus_f(fmaf(s1, wd, bd));
      S += delta;
      float corr = 0.0f;
#pragma unroll
      for (int k = 0; k < 8; ++k) {
        corr = fmaf(fast_exp2(Aln[2*k]   * S) * hin2[k].x, bc[l * NJ + 16 + 2*k],     corr);
        corr = fmaf(fast_exp2(Aln[2*k+1] * S) * hin2[k].y, bc[l * NJ + 16 + 2*k + 1], corr);
      }
      op[(size_t)l * D_DIM] = ylds[l * 256 + tid] + corr;
    }
  }
}

// ---------------------------------------------------------------------------
// Fallback trio (round-6, proven) — used only if cooperative launch fails.
// ---------------------------------------------------------------------------
template <int LC>
__global__ __launch_bounds__(256) void k_scan1(
    const float* __restrict__ x, const float* __restrict__ A_log,
    const float* __restrict__ W_d, const float* __restrict__ b_d,
    const float* __restrict__ BC33, float* __restrict__ DS,
    float* __restrict__ H, int NC) {
  const int cb = blockIdx.x % 3;
  const int c  = (blockIdx.x / 3) % NC;
  const int b  = blockIdx.x / (3 * NC);
  const int d  = cb * 256 + threadIdx.x;
  const float wd = W_d[d], bd = b_d[d];
  float Aln[N_ST];
#pragma unroll
  for (int n = 0; n < N_ST; ++n)
    Aln[n] = -__expf(A_log[d * N_ST + n]) * 1.44269504088896f;
  bool geom = true;
#pragma unroll
  for (int n = 1; n < N_ST; ++n) {
    float ref = (float)(n + 1) * Aln[0];
    geom = geom && (fabsf(Aln[n] - ref) <= 1e-4f * fabsf(ref) + 1e-12f);
  }
  const float a0 = Aln[0];
  float h[N_ST];
#pragma unroll
  for (int n = 0; n < N_ST; ++n) h[n] = 0.0f;
  float dsum = 0.0f;
  const int l0 = c * LC;
  const float* bc = BC33 + (size_t)(b * L_SEQ + l0) * NJ;
  const float* xp = x + (size_t)(b * L_SEQ + l0) * D_DIM + d;
  if (geom) {
#pragma unroll 8
    for (int l = 0; l < LC; ++l) {
      float s1 = bc[l * NJ + 32];
      float delta = softplus_f(fmaf(s1, wd, bd));
      float f = delta * xp[(size_t)l * D_DIM];
      dsum += delta;
      float pw[N_ST];
      pow_tree(fast_exp2(a0 * delta), pw);
#pragma unroll
      for (int n = 0; n < N_ST; ++n)
        h[n] = fmaf(pw[n], h[n], f * bc[l * NJ + n]);
    }
  } else {
#pragma unroll 4
    for (int l = 0; l < LC; ++l) {
      float s1 = bc[l * NJ + 32];
      float delta = softplus_f(fmaf(s1, wd, bd));
      float f = delta * xp[(size_t)l * D_DIM];
      dsum += delta;
#pragma unroll
      for (int n = 0; n < N_ST; ++n)
        h[n] = fmaf(fast_exp2(delta * Aln[n]), h[n], f * bc[l * NJ + n]);
    }
  }
  DS[((size_t)b * NC + c) * D_DIM + d] = dsum;
  size_t base = ((size_t)(b * NC + c) * D_DIM + d) * N_ST;
  float4* H4 = (float4*)(H + base);
#pragma unroll
  for (int q = 0; q < 4; ++q)
    H4[q] = make_float4(h[4*q], h[4*q+1], h[4*q+2], h[4*q+3]);
}

__global__ __launch_bounds__(256) void k_combine(
    const float* __restrict__ A_log, const float* __restrict__ DS,
    float* __restrict__ H, int NC) {
  const int b  = blockIdx.x / 48;
  const int tl = (blockIdx.x % 48) * 256 + threadIdx.x;
  const int d = tl >> 4, n = tl & 15;
  const float Aln = -__expf(A_log[d * N_ST + n]) * 1.44269504088896f;
  const float* dsp = DS + (size_t)b * NC * D_DIM + d;
  float* Hp = H + (size_t)b * NC * DN + tl;
  float h = 0.0f;
  float ds_c = dsp[0];
  float hold = Hp[0];
#pragma unroll 8
  for (int c = 0; c < NC; ++c) {
    float ds_n = 0.0f, hold_n = 0.0f;
    if (c + 1 < NC) {
      ds_n   = dsp[(size_t)(c + 1) * D_DIM];
      hold_n = Hp[(size_t)(c + 1) * DN];
    }
    float p = fast_exp2(Aln * ds_c);
    Hp[(size_t)c * DN] = h;
    h = fmaf(p, h, hold);
    ds_c = ds_n; hold = hold_n;
  }
}

template <int LC>
__global__ __launch_bounds__(256) void k_scan2(
    const float* __restrict__ x, const float* __restrict__ A_log,
    const float* __restrict__ W_d, const float* __restrict__ b_d,
    const float* __restrict__ BC33, const float* __restrict__ HIN,
    float* __restrict__ out, int NC) {
  const int cb = blockIdx.x % 3;
  const int c  = (blockIdx.x / 3) % NC;
  const int b  = blockIdx.x / (3 * NC);
  const int d  = cb * 256 + threadIdx.x;
  const float wd = W_d[d], bd = b_d[d];
  float Aln[N_ST];
#pragma unroll
  for (int n = 0; n < N_ST; ++n)
    Aln[n] = -__expf(A_log[d * N_ST + n]) * 1.44269504088896f;
  bool geom = true;
#pragma unroll
  for (int n = 1; n < N_ST; ++n) {
    float ref = (float)(n + 1) * Aln[0];
    geom = geom && (fabsf(Aln[n] - ref) <= 1e-4f * fabsf(ref) + 1e-12f);
  }
  const float a0 = Aln[0];
  float h[N_ST];
  size_t base = ((size_t)(b * NC + c) * D_DIM + d) * N_ST;
  const float4* HIN4 = (const float4*)(HIN + base);
#pragma unroll
  for (int q = 0; q < 4; ++q) {
    float4 v = HIN4[q];
    h[4*q] = v.x; h[4*q+1] = v.y; h[4*q+2] = v.z; h[4*q+3] = v.w;
  }
  const int l0 = c * LC;
  const float* bc = BC33 + (size_t)(b * L_SEQ + l0) * NJ;
  const float* xp = x + (size_t)(b * L_SEQ + l0) * D_DIM + d;
  float* op = out + (size_t)(b * L_SEQ + l0) * D_DIM + d;
  if (geom) {
#pragma unroll 8
    for (int l = 0; l < LC; ++l) {
      float s1 = bc[l * NJ + 32];
      float delta = softplus_f(fmaf(s1, wd, bd));
      float f = delta * xp[(size_t)l * D_DIM];
      float pw[N_ST];
      pow_tree(fast_exp2(a0 * delta), pw);
      float y = 0.0f;
#pragma unroll
      for (int n = 0; n < N_ST; ++n) {
        h[n] = fmaf(pw[n], h[n], f * bc[l * NJ + n]);
        y = fmaf(h[n], bc[l * NJ + 16 + n], y);
      }
      op[(size_t)l * D_DIM] = y;
    }
  } else {
#pragma unroll 4
    for (int l = 0; l < LC; ++l) {
      float s1 = bc[l * NJ + 32];
      float delta = softplus_f(fmaf(s1, wd, bd));
      float f = delta * xp[(size_t)l * D_DIM];
      float y = 0.0f;
#pragma unroll
      for (int n = 0; n < N_ST; ++n) {
        h[n] = fmaf(fast_exp2(delta * Aln[n]), h[n], f * bc[l * NJ + n]);
        y = fmaf(h[n], bc[l * NJ + 16 + n], y);
      }
      op[(size_t)l * D_DIM] = y;
    }
  }
}

// ---------------------------------------------------------------------------
extern "C" void kernel_launch(void* const* d_in, const int* in_sizes, int n_in,
                              void* d_out, int out_size, void* d_ws, size_t ws_size,
                              hipStream_t stream) {
  const float* x     = (const float*)d_in[0];
  const float* A_log = (const float*)d_in[1];
  const float* W_bc  = (const float*)d_in[2];
  const float* b_bc  = (const float*)d_in[3];
  const float* W_1   = (const float*)d_in[4];
  const float* b_1   = (const float*)d_in[5];
  const float* W_d   = (const float*)d_in[6];
  const float* b_d   = (const float*)d_in[7];
  float* out = (float*)d_out;
  float* ws  = (float*)d_ws;

  int NC = 64;
  {
    size_t need = (9ull * PROJ_ELEMS + (3072ull + 49152ull) * 64) * 4ull;
    if (ws_size < need) NC = 32;
  }

  float* BC33 = ws;
  float* PBC  = ws + PROJ_ELEMS;
  float* DSb  = PBC + (size_t)DSPLIT * PROJ_ELEMS;
  float* H    = DSb + (size_t)3072 * NC;

  k_proj_gemm<<<(NROWS / RB) * DSPLIT, 256, 0, stream>>>(x, W_bc, W_1, PBC);
  k_proj_reduce<<<PROJ_ELEMS / 256, 256, 0, stream>>>(PBC, b_bc, b_1, BC33);

  const int gs = 3 * NB * NC;
  const float* xa = x; const float* ala = A_log;
  const float* wda = W_d; const float* bda = b_d;
  const float* bca = BC33; float* dsa = DSb; float* ha = H; float* oa = out;
  void* args[] = {(void*)&xa, (void*)&ala, (void*)&wda, (void*)&bda,
                  (void*)&bca, (void*)&dsa, (void*)&ha, (void*)&oa};

  hipError_t ce;
  if (NC == 64) {
    ce = hipLaunchCooperativeKernel(reinterpret_cast<void*>(&k_scan_coop<32>),
                                    dim3(gs), dim3(256), args, 0, stream);
  } else {
    ce = hipLaunchCooperativeKernel(reinterpret_cast<void*>(&k_scan_coop<64>),
                                    dim3(gs), dim3(256), args, 0, stream);
  }
  if (ce != hipSuccess) {
    (void)hipGetLastError();   // clear sticky error; fall back to proven trio
    if (NC == 64) {
      k_scan1<32><<<gs, 256, 0, stream>>>(x, A_log, W_d, b_d, BC33, DSb, H, NC);
      k_combine<<<192, 256, 0, stream>>>(A_log, DSb, H, NC);
      k_scan2<32><<<gs, 256, 0, stream>>>(x, A_log, W_d, b_d, BC33, H, out, NC);
    } else {
      k_scan1<64><<<gs, 256, 0, stream>>>(x, A_log, W_d, b_d, BC33, DSb, H, NC);
      k_combine<<<192, 256, 0, stream>>>(A_log, DSb, H, NC);
      k_scan2<64><<<gs, 256, 0, stream>>>(x, A_log, W_d, b_d, BC33, H, out, NC);
    }
  }
}

// Round 8
// 151.886 us; speedup vs baseline: 2.3672x; 2.3672x over previous
//
#include <hip/hip_runtime.h>

#define L_SEQ 2048
#define D_DIM 768
#define N_ST 16
#define NB 4
#define NJ 33            // 16 B + 16 C + 1 s1 (logical)
#define BCS 48           // padded row stride (192 B -> every float4 16B-aligned)
#define NROWS (NB * L_SEQ)          // 8192
#define PROJ_ELEMS (NROWS * NJ)     // 270336
#define DN (D_DIM * N_ST)           // 12288

// proj GEMM tiling
#define DSPLIT 8
#define DSEG (D_DIM / DSPLIT)       // 96
#define DK 32
#define NCHUNK (DSEG / DK)          // 3
#define RB 128
#define XST 132
#define WST 64

typedef float v2f __attribute__((ext_vector_type(2)));

__device__ __forceinline__ float fast_exp2(float x) {
#if __has_builtin(__builtin_amdgcn_exp2f)
  return __builtin_amdgcn_exp2f(x);
#else
  return __expf(x * 0.69314718055994531f);
#endif
}

// softplus = log2(1+2^(v*log2e))*ln2; guard large v (exp2 -> inf)
__device__ __forceinline__ float softplus_f(float v) {
  float e = fast_exp2(v * 1.44269504088896f);
  float l = __log2f(1.0f + e) * 0.69314718055994531f;
  return (v > 15.0f) ? v : l;
}

// pw2[k] = {e1^(2k+1), e1^(2k+2)} via log-depth tree
__device__ __forceinline__ void pow_tree2(float e1, v2f pw2[8]) {
  float e2s = e1 * e1;
  float e4s = e2s * e2s;
  float e8s = e4s * e4s;
  v2f s2 = {e2s, e2s}, s4 = {e4s, e4s}, s8 = {e8s, e8s};
  pw2[0] = (v2f){e1, e2s};
  pw2[1] = pw2[0] * s2;
  pw2[2] = pw2[0] * s4;
  pw2[3] = pw2[1] * s4;
  pw2[4] = pw2[0] * s8;
  pw2[5] = pw2[1] * s8;
  pw2[6] = pw2[2] * s8;
  pw2[7] = pw2[3] * s8;
}

// ---------------------------------------------------------------------------
// Projection GEMM, K-split 8 ways. (Verified round 3.)
// ---------------------------------------------------------------------------
__global__ __launch_bounds__(256) void k_proj_gemm(
    const float* __restrict__ x, const float* __restrict__ W_bc,
    const float* __restrict__ W_1, float* __restrict__ PBC) {
  __shared__ float xs_t[DK * XST];
  __shared__ float ws_t[DK * WST];

  const int ds  = blockIdx.x % DSPLIT;
  const int rb0 = (blockIdx.x / DSPLIT) * RB;
  const int dbase = ds * DSEG;
  const int tid = threadIdx.x;
  const int rg = tid & 31;
  const int jg = tid >> 5;

  float acc[4][5];
#pragma unroll
  for (int i = 0; i < 4; ++i)
#pragma unroll
    for (int k = 0; k < 5; ++k) acc[i][k] = 0.0f;

  const int lrow = tid >> 1;
  const int lhalf = (tid & 1) * 16;
  const float* xg_row = x + (size_t)(rb0 + lrow) * D_DIM + dbase + lhalf;

  for (int ch = 0; ch < NCHUNK; ++ch) {
    const int dc = dbase + ch * DK;
    float4 xv[4];
#pragma unroll
    for (int q = 0; q < 4; ++q)
      xv[q] = *(const float4*)(xg_row + ch * DK + q * 4);
    float wv[8];
    int widx[8];
#pragma unroll
    for (int u = 0; u < 8; ++u) {
      int idx = tid + u * 256;
      int dk = idx >> 6, slot = idx & 63;
      int wjg = slot >> 3, wk = slot & 7;
      int j = wjg + 8 * wk;
      float v = 0.0f;
      if (wk < 5) {
        if (j < 32)       v = W_bc[(size_t)j * D_DIM + dc + dk];
        else if (j == 32) v = W_1[dc + dk];
      }
      wv[u] = v; widx[u] = dk * WST + slot;
    }
    __syncthreads();
#pragma unroll
    for (int q = 0; q < 4; ++q) {
      xs_t[(lhalf + q * 4 + 0) * XST + lrow] = xv[q].x;
      xs_t[(lhalf + q * 4 + 1) * XST + lrow] = xv[q].y;
      xs_t[(lhalf + q * 4 + 2) * XST + lrow] = xv[q].z;
      xs_t[(lhalf + q * 4 + 3) * XST + lrow] = xv[q].w;
    }
#pragma unroll
    for (int u = 0; u < 8; ++u) ws_t[widx[u]] = wv[u];
    __syncthreads();
#pragma unroll 8
    for (int dk = 0; dk < DK; ++dk) {
      float4 xr = *(const float4*)&xs_t[dk * XST + rg * 4];
      float4 wr = *(const float4*)&ws_t[dk * WST + jg * 8];
      float w4  = ws_t[dk * WST + jg * 8 + 4];
      float xa[4] = {xr.x, xr.y, xr.z, xr.w};
      float wa[5] = {wr.x, wr.y, wr.z, wr.w, w4};
#pragma unroll
      for (int i = 0; i < 4; ++i)
#pragma unroll
        for (int k = 0; k < 5; ++k)
          acc[i][k] = fmaf(xa[i], wa[k], acc[i][k]);
    }
  }

  float* pb = PBC + (size_t)ds * PROJ_ELEMS;
#pragma unroll
  for (int i = 0; i < 4; ++i) {
    int row = rb0 + rg * 4 + i;
#pragma unroll
    for (int k = 0; k < 5; ++k) {
      int j = jg + 8 * k;
      if (k < 4 || jg == 0) pb[(size_t)row * NJ + j] = acc[i][k];
    }
  }
}

// Sum K-split partials + bias -> padded BC48 rows (stride 48 floats, 192 B).
__global__ __launch_bounds__(256) void k_proj_reduce(
    const float* __restrict__ PBC, const float* __restrict__ b_bc,
    const float* __restrict__ b_1, float* __restrict__ BC48) {
  const int idx = blockIdx.x * 256 + threadIdx.x;   // < PROJ_ELEMS
  const int row = idx / NJ;
  const int j = idx - row * NJ;
  float s = 0.0f;
#pragma unroll
  for (int k = 0; k < DSPLIT; ++k) s += PBC[(size_t)k * PROJ_ELEMS + idx];
  s += (j < 32) ? b_bc[j] : b_1[0];
  BC48[(size_t)row * BCS + j] = s;
}

// ---------------------------------------------------------------------------
// Pass 1: per-chunk local scan, h0=0. bc row read as 8 aligned float4
// broadcasts + 1 dword. Emits H (chunk-end state) and DS (delta sum).
// ---------------------------------------------------------------------------
template <int LC>
__global__ __launch_bounds__(256) void k_scan1(
    const float* __restrict__ x, const float* __restrict__ A_log,
    const float* __restrict__ W_d, const float* __restrict__ b_d,
    const float* __restrict__ BC48, float* __restrict__ DS,
    float* __restrict__ H, int NC) {
  const int cb = blockIdx.x % 3;
  const int c  = (blockIdx.x / 3) % NC;
  const int b  = blockIdx.x / (3 * NC);
  const int d  = cb * 256 + threadIdx.x;

  const float wd = W_d[d], bd = b_d[d];
  float Aln[N_ST];
  {
    const float4* al4 = (const float4*)(A_log + (size_t)d * N_ST);
#pragma unroll
    for (int q = 0; q < 4; ++q) {
      float4 v = al4[q];
      Aln[4*q+0] = -__expf(v.x) * 1.44269504088896f;
      Aln[4*q+1] = -__expf(v.y) * 1.44269504088896f;
      Aln[4*q+2] = -__expf(v.z) * 1.44269504088896f;
      Aln[4*q+3] = -__expf(v.w) * 1.44269504088896f;
    }
  }
  bool geom = true;
#pragma unroll
  for (int n = 1; n < N_ST; ++n) {
    float ref = (float)(n + 1) * Aln[0];
    geom = geom && (fabsf(Aln[n] - ref) <= 1e-4f * fabsf(ref) + 1e-12f);
  }
  const float a0 = Aln[0];

  v2f h2[8];
#pragma unroll
  for (int k = 0; k < 8; ++k) h2[k] = (v2f){0.0f, 0.0f};
  float dsum = 0.0f;

  const int l0 = c * LC;
  const float* bc = BC48 + (size_t)(b * L_SEQ + l0) * BCS;
  const float* xp = x + (size_t)(b * L_SEQ + l0) * D_DIM + d;

  if (geom) {
#pragma unroll 8
    for (int l = 0; l < LC; ++l) {
      const float* r = bc + l * BCS;
      float4 B0 = *(const float4*)(r + 0);
      float4 B1 = *(const float4*)(r + 4);
      float4 B2 = *(const float4*)(r + 8);
      float4 B3 = *(const float4*)(r + 12);
      float s1 = r[32];
      float delta = softplus_f(fmaf(s1, wd, bd));
      float xv = xp[(size_t)l * D_DIM];
      float f = delta * xv;
      dsum += delta;
      v2f pw2[8];
      pow_tree2(fast_exp2(a0 * delta), pw2);
      v2f f2 = {f, f};
      h2[0] = pw2[0] * h2[0] + f2 * (v2f){B0.x, B0.y};
      h2[1] = pw2[1] * h2[1] + f2 * (v2f){B0.z, B0.w};
      h2[2] = pw2[2] * h2[2] + f2 * (v2f){B1.x, B1.y};
      h2[3] = pw2[3] * h2[3] + f2 * (v2f){B1.z, B1.w};
      h2[4] = pw2[4] * h2[4] + f2 * (v2f){B2.x, B2.y};
      h2[5] = pw2[5] * h2[5] + f2 * (v2f){B2.z, B2.w};
      h2[6] = pw2[6] * h2[6] + f2 * (v2f){B3.x, B3.y};
      h2[7] = pw2[7] * h2[7] + f2 * (v2f){B3.z, B3.w};
    }
  } else {
#pragma unroll 4
    for (int l = 0; l < LC; ++l) {
      const float* r = bc + l * BCS;
      float s1 = r[32];
      float delta = softplus_f(fmaf(s1, wd, bd));
      float f = delta * xp[(size_t)l * D_DIM];
      dsum += delta;
#pragma unroll
      for (int k = 0; k < 8; ++k) {
        h2[k].x = fmaf(fast_exp2(delta * Aln[2*k]),   h2[k].x, f * r[2*k]);
        h2[k].y = fmaf(fast_exp2(delta * Aln[2*k+1]), h2[k].y, f * r[2*k+1]);
      }
    }
  }

  DS[((size_t)b * NC + c) * D_DIM + d] = dsum;
  size_t base = ((size_t)(b * NC + c) * D_DIM + d) * N_ST;
  float4* H4 = (float4*)(H + base);
#pragma unroll
  for (int q = 0; q < 4; ++q)
    H4[q] = make_float4(h2[2*q].x, h2[2*q].y, h2[2*q+1].x, h2[2*q+1].y);
}

// ---------------------------------------------------------------------------
// Pass 2: inter-chunk combine, in-place, 8-deep prefetch. NC multiple of 8.
// ---------------------------------------------------------------------------
__global__ __launch_bounds__(256) void k_combine(
    const float* __restrict__ A_log, const float* __restrict__ DS,
    float* __restrict__ H, int NC) {
  const int b  = blockIdx.x / 48;
  const int tl = (blockIdx.x % 48) * 256 + threadIdx.x;   // 0..12287
  const int d = tl >> 4, n = tl & 15;
  const float Aln1 = -__expf(A_log[d * N_ST + n]) * 1.44269504088896f;
  const float* dsp = DS + (size_t)b * NC * D_DIM + d;
  float* Hp = H + (size_t)b * NC * DN + tl;

  float h = 0.0f;
  float pds[8], ph[8];
#pragma unroll
  for (int k = 0; k < 8; ++k) {
    pds[k] = dsp[(size_t)k * D_DIM];
    ph[k]  = Hp[(size_t)k * DN];
  }
  for (int g = 0; g < NC; g += 8) {
    float nds[8], nh[8];
    if (g + 8 < NC) {
#pragma unroll
      for (int k = 0; k < 8; ++k) {
        nds[k] = dsp[(size_t)(g + 8 + k) * D_DIM];
        nh[k]  = Hp[(size_t)(g + 8 + k) * DN];
      }
    }
#pragma unroll
    for (int k = 0; k < 8; ++k) {
      float p = fast_exp2(Aln1 * pds[k]);
      Hp[(size_t)(g + k) * DN] = h;                 // incoming state
      h = fmaf(p, h, ph[k]);
    }
#pragma unroll
    for (int k = 0; k < 8; ++k) { pds[k] = nds[k]; ph[k] = nh[k]; }
  }
}

// ---------------------------------------------------------------------------
// Pass 3: re-run the scan from the incoming state, emit y.
// ---------------------------------------------------------------------------
template <int LC>
__global__ __launch_bounds__(256) void k_scan2(
    const float* __restrict__ x, const float* __restrict__ A_log,
    const float* __restrict__ W_d, const float* __restrict__ b_d,
    const float* __restrict__ BC48, const float* __restrict__ HIN,
    float* __restrict__ out, int NC) {
  const int cb = blockIdx.x % 3;
  const int c  = (blockIdx.x / 3) % NC;
  const int b  = blockIdx.x / (3 * NC);
  const int d  = cb * 256 + threadIdx.x;

  const float wd = W_d[d], bd = b_d[d];
  float Aln[N_ST];
  {
    const float4* al4 = (const float4*)(A_log + (size_t)d * N_ST);
#pragma unroll
    for (int q = 0; q < 4; ++q) {
      float4 v = al4[q];
      Aln[4*q+0] = -__expf(v.x) * 1.44269504088896f;
      Aln[4*q+1] = -__expf(v.y) * 1.44269504088896f;
      Aln[4*q+2] = -__expf(v.z) * 1.44269504088896f;
      Aln[4*q+3] = -__expf(v.w) * 1.44269504088896f;
    }
  }
  bool geom = true;
#pragma unroll
  for (int n = 1; n < N_ST; ++n) {
    float ref = (float)(n + 1) * Aln[0];
    geom = geom && (fabsf(Aln[n] - ref) <= 1e-4f * fabsf(ref) + 1e-12f);
  }
  const float a0 = Aln[0];

  v2f h2[8];
  {
    size_t base = ((size_t)(b * NC + c) * D_DIM + d) * N_ST;
    const float4* HIN4 = (const float4*)(HIN + base);
#pragma unroll
    for (int q = 0; q < 4; ++q) {
      float4 v = HIN4[q];
      h2[2*q]   = (v2f){v.x, v.y};
      h2[2*q+1] = (v2f){v.z, v.w};
    }
  }

  const int l0 = c * LC;
  const float* bc = BC48 + (size_t)(b * L_SEQ + l0) * BCS;
  const float* xp = x + (size_t)(b * L_SEQ + l0) * D_DIM + d;
  float* op = out + (size_t)(b * L_SEQ + l0) * D_DIM + d;

  if (geom) {
#pragma unroll 8
    for (int l = 0; l < LC; ++l) {
      const float* r = bc + l * BCS;
      float4 B0 = *(const float4*)(r + 0);
      float4 B1 = *(const float4*)(r + 4);
      float4 B2 = *(const float4*)(r + 8);
      float4 B3 = *(const float4*)(r + 12);
      float4 C0 = *(const float4*)(r + 16);
      float4 C1 = *(const float4*)(r + 20);
      float4 C2 = *(const float4*)(r + 24);
      float4 C3 = *(const float4*)(r + 28);
      float s1 = r[32];
      float delta = softplus_f(fmaf(s1, wd, bd));
      float xv = xp[(size_t)l * D_DIM];
      float f = delta * xv;
      v2f pw2[8];
      pow_tree2(fast_exp2(a0 * delta), pw2);
      v2f f2 = {f, f};
      v2f y2 = {0.0f, 0.0f};
      h2[0] = pw2[0] * h2[0] + f2 * (v2f){B0.x, B0.y};  y2 += h2[0] * (v2f){C0.x, C0.y};
      h2[1] = pw2[1] * h2[1] + f2 * (v2f){B0.z, B0.w};  y2 += h2[1] * (v2f){C0.z, C0.w};
      h2[2] = pw2[2] * h2[2] + f2 * (v2f){B1.x, B1.y};  y2 += h2[2] * (v2f){C1.x, C1.y};
      h2[3] = pw2[3] * h2[3] + f2 * (v2f){B1.z, B1.w};  y2 += h2[3] * (v2f){C1.z, C1.w};
      h2[4] = pw2[4] * h2[4] + f2 * (v2f){B2.x, B2.y};  y2 += h2[4] * (v2f){C2.x, C2.y};
      h2[5] = pw2[5] * h2[5] + f2 * (v2f){B2.z, B2.w};  y2 += h2[5] * (v2f){C2.z, C2.w};
      h2[6] = pw2[6] * h2[6] + f2 * (v2f){B3.x, B3.y};  y2 += h2[6] * (v2f){C3.x, C3.y};
      h2[7] = pw2[7] * h2[7] + f2 * (v2f){B3.z, B3.w};  y2 += h2[7] * (v2f){C3.z, C3.w};
      op[(size_t)l * D_DIM] = y2.x + y2.y;
    }
  } else {
#pragma unroll 4
    for (int l = 0; l < LC; ++l) {
      const float* r = bc + l * BCS;
      float s1 = r[32];
      float delta = softplus_f(fmaf(s1, wd, bd));
      float f = delta * xp[(size_t)l * D_DIM];
      float y = 0.0f;
#pragma unroll
      for (int k = 0; k < 8; ++k) {
        h2[k].x = fmaf(fast_exp2(delta * Aln[2*k]),   h2[k].x, f * r[2*k]);
        h2[k].y = fmaf(fast_exp2(delta * Aln[2*k+1]), h2[k].y, f * r[2*k+1]);
        y = fmaf(h2[k].x, r[16 + 2*k], y);
        y = fmaf(h2[k].y, r[16 + 2*k + 1], y);
      }
      op[(size_t)l * D_DIM] = y;
    }
  }
}

// ---------------------------------------------------------------------------
extern "C" void kernel_launch(void* const* d_in, const int* in_sizes, int n_in,
                              void* d_out, int out_size, void* d_ws, size_t ws_size,
                              hipStream_t stream) {
  const float* x     = (const float*)d_in[0];
  const float* A_log = (const float*)d_in[1];
  const float* W_bc  = (const float*)d_in[2];
  const float* b_bc  = (const float*)d_in[3];
  const float* W_1   = (const float*)d_in[4];
  const float* b_1   = (const float*)d_in[5];
  const float* W_d   = (const float*)d_in[6];
  const float* b_d   = (const float*)d_in[7];
  float* out = (float*)d_out;
  float* ws  = (float*)d_ws;

  // ws (floats): BC48 393216 + PBC 8*270336 + DS 3072*NC + H 49152*NC
  int NC = 64;
  {
    size_t need = ((size_t)NROWS * BCS + 8ull * PROJ_ELEMS +
                   (3072ull + 49152ull) * 64) * 4ull;
    if (ws_size < need) NC = 32;
  }

  float* BC48 = ws;
  float* PBC  = ws + (size_t)NROWS * BCS;
  float* DSb  = PBC + (size_t)DSPLIT * PROJ_ELEMS;
  float* H    = DSb + (size_t)3072 * NC;

  k_proj_gemm<<<(NROWS / RB) * DSPLIT, 256, 0, stream>>>(x, W_bc, W_1, PBC);
  k_proj_reduce<<<(PROJ_ELEMS + 255) / 256, 256, 0, stream>>>(PBC, b_bc, b_1, BC48);

  const int gs = 3 * NB * NC;
  if (NC == 64) {
    k_scan1<32><<<gs, 256, 0, stream>>>(x, A_log, W_d, b_d, BC48, DSb, H, NC);
    k_combine<<<192, 256, 0, stream>>>(A_log, DSb, H, NC);
    k_scan2<32><<<gs, 256, 0, stream>>>(x, A_log, W_d, b_d, BC48, H, out, NC);
  } else {
    k_scan1<64><<<gs, 256, 0, stream>>>(x, A_log, W_d, b_d, BC48, DSb, H, NC);
    k_combine<<<192, 256, 0, stream>>>(A_log, DSb, H, NC);
    k_scan2<64><<<gs, 256, 0, stream>>>(x, A_log, W_d, b_d, BC48, H, out, NC);
  }
}

// Round 9
// 151.754 us; speedup vs baseline: 2.3692x; 1.0009x over previous
//
#include <hip/hip_runtime.h>

#define L_SEQ 2048
#define D_DIM 768
#define N_ST 16
#define NB 4
#define NJ 33            // 16 B + 16 C + 1 s1 (logical)
#define BCS 48           // padded row stride (192 B -> every float4 16B-aligned)
#define NROWS (NB * L_SEQ)          // 8192
#define PROJ_ELEMS (NROWS * NJ)     // 270336
#define DN (D_DIM * N_ST)           // 12288

// proj GEMM tiling
#define DSPLIT 8
#define DSEG (D_DIM / DSPLIT)       // 96
#define DK 32
#define NCHUNK (DSEG / DK)          // 3
#define RB 128
#define XST 132
#define WST 64

typedef float v2f __attribute__((ext_vector_type(2)));

__device__ __forceinline__ float fast_exp2(float x) {
#if __has_builtin(__builtin_amdgcn_exp2f)
  return __builtin_amdgcn_exp2f(x);
#else
  return __expf(x * 0.69314718055994531f);
#endif
}

// softplus = log2(1+2^(v*log2e))*ln2; guard large v (exp2 -> inf)
__device__ __forceinline__ float softplus_f(float v) {
  float e = fast_exp2(v * 1.44269504088896f);
  float l = __log2f(1.0f + e) * 0.69314718055994531f;
  return (v > 15.0f) ? v : l;
}

// pw2[k] = {e1^(2k+1), e1^(2k+2)} via log-depth tree
__device__ __forceinline__ void pow_tree2(float e1, v2f pw2[8]) {
  float e2s = e1 * e1;
  float e4s = e2s * e2s;
  float e8s = e4s * e4s;
  v2f s2 = {e2s, e2s}, s4 = {e4s, e4s}, s8 = {e8s, e8s};
  pw2[0] = (v2f){e1, e2s};
  pw2[1] = pw2[0] * s2;
  pw2[2] = pw2[0] * s4;
  pw2[3] = pw2[1] * s4;
  pw2[4] = pw2[0] * s8;
  pw2[5] = pw2[1] * s8;
  pw2[6] = pw2[2] * s8;
  pw2[7] = pw2[3] * s8;
}

// ---------------------------------------------------------------------------
// Projection GEMM, K-split 8 ways. (Verified round 3.)
// ---------------------------------------------------------------------------
__global__ __launch_bounds__(256) void k_proj_gemm(
    const float* __restrict__ x, const float* __restrict__ W_bc,
    const float* __restrict__ W_1, float* __restrict__ PBC) {
  __shared__ float xs_t[DK * XST];
  __shared__ float ws_t[DK * WST];

  const int ds  = blockIdx.x % DSPLIT;
  const int rb0 = (blockIdx.x / DSPLIT) * RB;
  const int dbase = ds * DSEG;
  const int tid = threadIdx.x;
  const int rg = tid & 31;
  const int jg = tid >> 5;

  float acc[4][5];
#pragma unroll
  for (int i = 0; i < 4; ++i)
#pragma unroll
    for (int k = 0; k < 5; ++k) acc[i][k] = 0.0f;

  const int lrow = tid >> 1;
  const int lhalf = (tid & 1) * 16;
  const float* xg_row = x + (size_t)(rb0 + lrow) * D_DIM + dbase + lhalf;

  for (int ch = 0; ch < NCHUNK; ++ch) {
    const int dc = dbase + ch * DK;
    float4 xv[4];
#pragma unroll
    for (int q = 0; q < 4; ++q)
      xv[q] = *(const float4*)(xg_row + ch * DK + q * 4);
    float wv[8];
    int widx[8];
#pragma unroll
    for (int u = 0; u < 8; ++u) {
      int idx = tid + u * 256;
      int dk = idx >> 6, slot = idx & 63;
      int wjg = slot >> 3, wk = slot & 7;
      int j = wjg + 8 * wk;
      float v = 0.0f;
      if (wk < 5) {
        if (j < 32)       v = W_bc[(size_t)j * D_DIM + dc + dk];
        else if (j == 32) v = W_1[dc + dk];
      }
      wv[u] = v; widx[u] = dk * WST + slot;
    }
    __syncthreads();
#pragma unroll
    for (int q = 0; q < 4; ++q) {
      xs_t[(lhalf + q * 4 + 0) * XST + lrow] = xv[q].x;
      xs_t[(lhalf + q * 4 + 1) * XST + lrow] = xv[q].y;
      xs_t[(lhalf + q * 4 + 2) * XST + lrow] = xv[q].z;
      xs_t[(lhalf + q * 4 + 3) * XST + lrow] = xv[q].w;
    }
#pragma unroll
    for (int u = 0; u < 8; ++u) ws_t[widx[u]] = wv[u];
    __syncthreads();
#pragma unroll 8
    for (int dk = 0; dk < DK; ++dk) {
      float4 xr = *(const float4*)&xs_t[dk * XST + rg * 4];
      float4 wr = *(const float4*)&ws_t[dk * WST + jg * 8];
      float w4  = ws_t[dk * WST + jg * 8 + 4];
      float xa[4] = {xr.x, xr.y, xr.z, xr.w};
      float wa[5] = {wr.x, wr.y, wr.z, wr.w, w4};
#pragma unroll
      for (int i = 0; i < 4; ++i)
#pragma unroll
        for (int k = 0; k < 5; ++k)
          acc[i][k] = fmaf(xa[i], wa[k], acc[i][k]);
    }
  }

  float* pb = PBC + (size_t)ds * PROJ_ELEMS;
#pragma unroll
  for (int i = 0; i < 4; ++i) {
    int row = rb0 + rg * 4 + i;
#pragma unroll
    for (int k = 0; k < 5; ++k) {
      int j = jg + 8 * k;
      if (k < 4 || jg == 0) pb[(size_t)row * NJ + j] = acc[i][k];
    }
  }
}

// Sum K-split partials + bias -> padded BC48 rows (stride 48 floats, 192 B).
__global__ __launch_bounds__(256) void k_proj_reduce(
    const float* __restrict__ PBC, const float* __restrict__ b_bc,
    const float* __restrict__ b_1, float* __restrict__ BC48) {
  const int idx = blockIdx.x * 256 + threadIdx.x;   // < PROJ_ELEMS
  const int row = idx / NJ;
  const int j = idx - row * NJ;
  float s = 0.0f;
#pragma unroll
  for (int k = 0; k < DSPLIT; ++k) s += PBC[(size_t)k * PROJ_ELEMS + idx];
  s += (j < 32) ? b_bc[j] : b_1[0];
  BC48[(size_t)row * BCS + j] = s;
}

// ---------------------------------------------------------------------------
// Pass 1: per-chunk local scan, h0=0. launch_bounds(256,6) -> VGPR<=85 so
// 6 blocks/CU co-reside (24 waves/CU) at the 1536-block grid.
// ---------------------------------------------------------------------------
template <int LC>
__global__ __launch_bounds__(256, 6) void k_scan1(
    const float* __restrict__ x, const float* __restrict__ A_log,
    const float* __restrict__ W_d, const float* __restrict__ b_d,
    const float* __restrict__ BC48, float* __restrict__ DS,
    float* __restrict__ H, int NC) {
  const int cb = blockIdx.x % 3;
  const int c  = (blockIdx.x / 3) % NC;
  const int b  = blockIdx.x / (3 * NC);
  const int d  = cb * 256 + threadIdx.x;

  const float wd = W_d[d], bd = b_d[d];
  float Aln[N_ST];
  {
    const float4* al4 = (const float4*)(A_log + (size_t)d * N_ST);
#pragma unroll
    for (int q = 0; q < 4; ++q) {
      float4 v = al4[q];
      Aln[4*q+0] = -__expf(v.x) * 1.44269504088896f;
      Aln[4*q+1] = -__expf(v.y) * 1.44269504088896f;
      Aln[4*q+2] = -__expf(v.z) * 1.44269504088896f;
      Aln[4*q+3] = -__expf(v.w) * 1.44269504088896f;
    }
  }
  bool geom = true;
#pragma unroll
  for (int n = 1; n < N_ST; ++n) {
    float ref = (float)(n + 1) * Aln[0];
    geom = geom && (fabsf(Aln[n] - ref) <= 1e-4f * fabsf(ref) + 1e-12f);
  }
  const float a0 = Aln[0];

  v2f h2[8];
#pragma unroll
  for (int k = 0; k < 8; ++k) h2[k] = (v2f){0.0f, 0.0f};
  float dsum = 0.0f;

  const int l0 = c * LC;
  const float* bc = BC48 + (size_t)(b * L_SEQ + l0) * BCS;
  const float* xp = x + (size_t)(b * L_SEQ + l0) * D_DIM + d;

  if (geom) {
#pragma unroll 8
    for (int l = 0; l < LC; ++l) {
      const float* r = bc + l * BCS;
      float4 B0 = *(const float4*)(r + 0);
      float4 B1 = *(const float4*)(r + 4);
      float4 B2 = *(const float4*)(r + 8);
      float4 B3 = *(const float4*)(r + 12);
      float s1 = r[32];
      float delta = softplus_f(fmaf(s1, wd, bd));
      float xv = xp[(size_t)l * D_DIM];
      float f = delta * xv;
      dsum += delta;
      v2f pw2[8];
      pow_tree2(fast_exp2(a0 * delta), pw2);
      v2f f2 = {f, f};
      h2[0] = pw2[0] * h2[0] + f2 * (v2f){B0.x, B0.y};
      h2[1] = pw2[1] * h2[1] + f2 * (v2f){B0.z, B0.w};
      h2[2] = pw2[2] * h2[2] + f2 * (v2f){B1.x, B1.y};
      h2[3] = pw2[3] * h2[3] + f2 * (v2f){B1.z, B1.w};
      h2[4] = pw2[4] * h2[4] + f2 * (v2f){B2.x, B2.y};
      h2[5] = pw2[5] * h2[5] + f2 * (v2f){B2.z, B2.w};
      h2[6] = pw2[6] * h2[6] + f2 * (v2f){B3.x, B3.y};
      h2[7] = pw2[7] * h2[7] + f2 * (v2f){B3.z, B3.w};
    }
  } else {
#pragma unroll 4
    for (int l = 0; l < LC; ++l) {
      const float* r = bc + l * BCS;
      float s1 = r[32];
      float delta = softplus_f(fmaf(s1, wd, bd));
      float f = delta * xp[(size_t)l * D_DIM];
      dsum += delta;
#pragma unroll
      for (int k = 0; k < 8; ++k) {
        h2[k].x = fmaf(fast_exp2(delta * Aln[2*k]),   h2[k].x, f * r[2*k]);
        h2[k].y = fmaf(fast_exp2(delta * Aln[2*k+1]), h2[k].y, f * r[2*k+1]);
      }
    }
  }

  DS[((size_t)b * NC + c) * D_DIM + d] = dsum;
  size_t base = ((size_t)(b * NC + c) * D_DIM + d) * N_ST;
  float4* H4 = (float4*)(H + base);
#pragma unroll
  for (int q = 0; q < 4; ++q)
    H4[q] = make_float4(h2[2*q].x, h2[2*q].y, h2[2*q+1].x, h2[2*q+1].y);
}

// ---------------------------------------------------------------------------
// Pass 2: inter-chunk combine, in-place, 8-deep prefetch. NC multiple of 8.
// ---------------------------------------------------------------------------
__global__ __launch_bounds__(256) void k_combine(
    const float* __restrict__ A_log, const float* __restrict__ DS,
    float* __restrict__ H, int NC) {
  const int b  = blockIdx.x / 48;
  const int tl = (blockIdx.x % 48) * 256 + threadIdx.x;   // 0..12287
  const int d = tl >> 4, n = tl & 15;
  const float Aln1 = -__expf(A_log[d * N_ST + n]) * 1.44269504088896f;
  const float* dsp = DS + (size_t)b * NC * D_DIM + d;
  float* Hp = H + (size_t)b * NC * DN + tl;

  float h = 0.0f;
  float pds[8], ph[8];
#pragma unroll
  for (int k = 0; k < 8; ++k) {
    pds[k] = dsp[(size_t)k * D_DIM];
    ph[k]  = Hp[(size_t)k * DN];
  }
  for (int g = 0; g < NC; g += 8) {
    float nds[8], nh[8];
    if (g + 8 < NC) {
#pragma unroll
      for (int k = 0; k < 8; ++k) {
        nds[k] = dsp[(size_t)(g + 8 + k) * D_DIM];
        nh[k]  = Hp[(size_t)(g + 8 + k) * DN];
      }
    }
#pragma unroll
    for (int k = 0; k < 8; ++k) {
      float p = fast_exp2(Aln1 * pds[k]);
      Hp[(size_t)(g + k) * DN] = h;                 // incoming state
      h = fmaf(p, h, ph[k]);
    }
#pragma unroll
    for (int k = 0; k < 8; ++k) { pds[k] = nds[k]; ph[k] = nh[k]; }
  }
}

// ---------------------------------------------------------------------------
// Pass 3: re-run the scan from the incoming state, emit y.
// ---------------------------------------------------------------------------
template <int LC>
__global__ __launch_bounds__(256, 6) void k_scan2(
    const float* __restrict__ x, const float* __restrict__ A_log,
    const float* __restrict__ W_d, const float* __restrict__ b_d,
    const float* __restrict__ BC48, const float* __restrict__ HIN,
    float* __restrict__ out, int NC) {
  const int cb = blockIdx.x % 3;
  const int c  = (blockIdx.x / 3) % NC;
  const int b  = blockIdx.x / (3 * NC);
  const int d  = cb * 256 + threadIdx.x;

  const float wd = W_d[d], bd = b_d[d];
  float Aln[N_ST];
  {
    const float4* al4 = (const float4*)(A_log + (size_t)d * N_ST);
#pragma unroll
    for (int q = 0; q < 4; ++q) {
      float4 v = al4[q];
      Aln[4*q+0] = -__expf(v.x) * 1.44269504088896f;
      Aln[4*q+1] = -__expf(v.y) * 1.44269504088896f;
      Aln[4*q+2] = -__expf(v.z) * 1.44269504088896f;
      Aln[4*q+3] = -__expf(v.w) * 1.44269504088896f;
    }
  }
  bool geom = true;
#pragma unroll
  for (int n = 1; n < N_ST; ++n) {
    float ref = (float)(n + 1) * Aln[0];
    geom = geom && (fabsf(Aln[n] - ref) <= 1e-4f * fabsf(ref) + 1e-12f);
  }
  const float a0 = Aln[0];

  v2f h2[8];
  {
    size_t base = ((size_t)(b * NC + c) * D_DIM + d) * N_ST;
    const float4* HIN4 = (const float4*)(HIN + base);
#pragma unroll
    for (int q = 0; q < 4; ++q) {
      float4 v = HIN4[q];
      h2[2*q]   = (v2f){v.x, v.y};
      h2[2*q+1] = (v2f){v.z, v.w};
    }
  }

  const int l0 = c * LC;
  const float* bc = BC48 + (size_t)(b * L_SEQ + l0) * BCS;
  const float* xp = x + (size_t)(b * L_SEQ + l0) * D_DIM + d;
  float* op = out + (size_t)(b * L_SEQ + l0) * D_DIM + d;

  if (geom) {
#pragma unroll 8
    for (int l = 0; l < LC; ++l) {
      const float* r = bc + l * BCS;
      float4 B0 = *(const float4*)(r + 0);
      float4 B1 = *(const float4*)(r + 4);
      float4 B2 = *(const float4*)(r + 8);
      float4 B3 = *(const float4*)(r + 12);
      float4 C0 = *(const float4*)(r + 16);
      float4 C1 = *(const float4*)(r + 20);
      float4 C2 = *(const float4*)(r + 24);
      float4 C3 = *(const float4*)(r + 28);
      float s1 = r[32];
      float delta = softplus_f(fmaf(s1, wd, bd));
      float xv = xp[(size_t)l * D_DIM];
      float f = delta * xv;
      v2f pw2[8];
      pow_tree2(fast_exp2(a0 * delta), pw2);
      v2f f2 = {f, f};
      v2f y2 = {0.0f, 0.0f};
      h2[0] = pw2[0] * h2[0] + f2 * (v2f){B0.x, B0.y};  y2 += h2[0] * (v2f){C0.x, C0.y};
      h2[1] = pw2[1] * h2[1] + f2 * (v2f){B0.z, B0.w};  y2 += h2[1] * (v2f){C0.z, C0.w};
      h2[2] = pw2[2] * h2[2] + f2 * (v2f){B1.x, B1.y};  y2 += h2[2] * (v2f){C1.x, C1.y};
      h2[3] = pw2[3] * h2[3] + f2 * (v2f){B1.z, B1.w};  y2 += h2[3] * (v2f){C1.z, C1.w};
      h2[4] = pw2[4] * h2[4] + f2 * (v2f){B2.x, B2.y};  y2 += h2[4] * (v2f){C2.x, C2.y};
      h2[5] = pw2[5] * h2[5] + f2 * (v2f){B2.z, B2.w};  y2 += h2[5] * (v2f){C2.z, C2.w};
      h2[6] = pw2[6] * h2[6] + f2 * (v2f){B3.x, B3.y};  y2 += h2[6] * (v2f){C3.x, C3.y};
      h2[7] = pw2[7] * h2[7] + f2 * (v2f){B3.z, B3.w};  y2 += h2[7] * (v2f){C3.z, C3.w};
      op[(size_t)l * D_DIM] = y2.x + y2.y;
    }
  } else {
#pragma unroll 4
    for (int l = 0; l < LC; ++l) {
      const float* r = bc + l * BCS;
      float s1 = r[32];
      float delta = softplus_f(fmaf(s1, wd, bd));
      float f = delta * xp[(size_t)l * D_DIM];
      float y = 0.0f;
#pragma unroll
      for (int k = 0; k < 8; ++k) {
        h2[k].x = fmaf(fast_exp2(delta * Aln[2*k]),   h2[k].x, f * r[2*k]);
        h2[k].y = fmaf(fast_exp2(delta * Aln[2*k+1]), h2[k].y, f * r[2*k+1]);
        y = fmaf(h2[k].x, r[16 + 2*k], y);
        y = fmaf(h2[k].y, r[16 + 2*k + 1], y);
      }
      op[(size_t)l * D_DIM] = y;
    }
  }
}

// ---------------------------------------------------------------------------
extern "C" void kernel_launch(void* const* d_in, const int* in_sizes, int n_in,
                              void* d_out, int out_size, void* d_ws, size_t ws_size,
                              hipStream_t stream) {
  const float* x     = (const float*)d_in[0];
  const float* A_log = (const float*)d_in[1];
  const float* W_bc  = (const float*)d_in[2];
  const float* b_bc  = (const float*)d_in[3];
  const float* W_1   = (const float*)d_in[4];
  const float* b_1   = (const float*)d_in[5];
  const float* W_d   = (const float*)d_in[6];
  const float* b_d   = (const float*)d_in[7];
  float* out = (float*)d_out;
  float* ws  = (float*)d_ws;

  // ws (floats): BC48 393216 + PBC 8*270336 + DS 3072*NC + H 49152*NC
  // NC=128 -> 1536 scan blocks = 6 blocks/CU = 24 waves/CU.
  int NC = 128;
  {
    size_t need = ((size_t)NROWS * BCS + 8ull * PROJ_ELEMS +
                   (3072ull + 49152ull) * 128) * 4ull;
    if (ws_size < need) NC = 64;
  }

  float* BC48 = ws;
  float* PBC  = ws + (size_t)NROWS * BCS;
  float* DSb  = PBC + (size_t)DSPLIT * PROJ_ELEMS;
  float* H    = DSb + (size_t)3072 * NC;

  k_proj_gemm<<<(NROWS / RB) * DSPLIT, 256, 0, stream>>>(x, W_bc, W_1, PBC);
  k_proj_reduce<<<(PROJ_ELEMS + 255) / 256, 256, 0, stream>>>(PBC, b_bc, b_1, BC48);

  const int gs = 3 * NB * NC;
  if (NC == 128) {
    k_scan1<16><<<gs, 256, 0, stream>>>(x, A_log, W_d, b_d, BC48, DSb, H, NC);
    k_combine<<<192, 256, 0, stream>>>(A_log, DSb, H, NC);
    k_scan2<16><<<gs, 256, 0, stream>>>(x, A_log, W_d, b_d, BC48, H, out, NC);
  } else {
    k_scan1<32><<<gs, 256, 0, stream>>>(x, A_log, W_d, b_d, BC48, DSb, H, NC);
    k_combine<<<192, 256, 0, stream>>>(A_log, DSb, H, NC);
    k_scan2<32><<<gs, 256, 0, stream>>>(x, A_log, W_d, b_d, BC48, H, out, NC);
  }
}